// Round 5
// baseline (96.219 us; speedup 1.0000x reference)
//
#include <hip/hip_runtime.h>
#include <math.h>

#define HH 512
#define WW 512
#define NB 8
#define NC 3
#define HW (HH*WW)

#define RSTRIP 16                         // output rows per wave
#define CSTRIP 62                         // output cols per wave
#define NROWS (HH/RSTRIP)                 // 32
#define NCOLS ((WW + CSTRIP - 1)/CSTRIP)  // 9

typedef float float4u __attribute__((ext_vector_type(4), aligned(4)));

// Register row-streaming separable conv; one wave per 62x16 strip.
// CS: column window fully in-bounds (no clamps/masks). RS: all rows in-bounds.
template<bool CS, bool RS>
__device__ __forceinline__ void gm_strip(
    const float* __restrict__ ip0, const float* __restrict__ ip1,
    const float* __restrict__ ip2, const double* g,
    int lane, int R0, int cl, int b,
    double* __restrict__ GM, unsigned char* __restrict__ KP)
{
    int cidx[9]; bool cmask[9];
    bool cml, cmr, lane_out;
    if (CS) {
        cml = true; cmr = true;
        lane_out = (lane >= 1) && (lane <= CSTRIP);
    } else {
#pragma unroll
        for (int k = 0; k < 9; ++k) {
            int cc = cl - 4 + k;
            cmask[k] = ((unsigned)cc < (unsigned)WW);
            int cc2 = cc < 0 ? 0 : cc;
            cidx[k] = cc2 > (WW - 1) ? (WW - 1) : cc2;
        }
        cml = ((unsigned)(cl - 1) < (unsigned)WW);
        cmr = ((unsigned)(cl + 1) < (unsigned)WW);
        lane_out = (lane >= 1) && (lane <= CSTRIP) && (cl < WW);
    }

    double hb[3][9];   // h-blur ring: row rbase+ph -> slot ph
    double vb[3][3];   // v-blur ring: row r-4 -> slot (ph+2)%3
#pragma unroll
    for (int c = 0; c < 3; ++c) {
#pragma unroll
        for (int k = 0; k < 9; ++k) hb[c][k] = 0.0;
#pragma unroll
        for (int k = 0; k < 3; ++k) vb[c][k] = 0.0;
    }

    const double t225 = 0.41421356237309503;   // tan(22.5 deg)
    const double t675 = 2.414213562373095;     // tan(67.5 deg)

    // phase body; ph compile-time after inlining from unrolled loops
    auto PHASE = [&](int r, int ph, bool doV, bool doS) {
        // ---- h-blur of img row r -> hb[c][ph]
        bool rin = RS ? true : ((unsigned)r < (unsigned)HH);
        if (rin) {
            const size_t ro = (size_t)r * WW;
            if (CS) {
                const float* rp0 = ip0 + ro + (cl - 4);
                const float* rp1 = ip1 + ro + (cl - 4);
                const float* rp2 = ip2 + ro + (cl - 4);
                float4u A0 = *(const float4u*)rp0, B0 = *(const float4u*)(rp0 + 4);
                float4u A1 = *(const float4u*)rp1, B1 = *(const float4u*)(rp1 + 4);
                float4u A2 = *(const float4u*)rp2, B2 = *(const float4u*)(rp2 + 4);
                float e0 = rp0[8], e1 = rp1[8], e2 = rp2[8];
                double a0 = 0.0, a1 = 0.0, a2 = 0.0;
#pragma unroll
                for (int k = 0; k < 9; ++k) {
                    float v0 = k < 4 ? A0[k] : (k < 8 ? B0[k - 4] : e0);
                    float v1 = k < 4 ? A1[k] : (k < 8 ? B1[k - 4] : e1);
                    float v2 = k < 4 ? A2[k] : (k < 8 ? B2[k - 4] : e2);
                    a0 = fma(g[k], (double)v0, a0);
                    a1 = fma(g[k], (double)v1, a1);
                    a2 = fma(g[k], (double)v2, a2);
                }
                hb[0][ph] = a0; hb[1][ph] = a1; hb[2][ph] = a2;
            } else {
                float v0[9], v1[9], v2[9];
#pragma unroll
                for (int k = 0; k < 9; ++k) {
                    v0[k] = ip0[ro + cidx[k]];
                    v1[k] = ip1[ro + cidx[k]];
                    v2[k] = ip2[ro + cidx[k]];
                }
                double a0 = 0.0, a1 = 0.0, a2 = 0.0;
#pragma unroll
                for (int k = 0; k < 9; ++k) {
                    a0 = fma(g[k], (double)(cmask[k] ? v0[k] : 0.0f), a0);
                    a1 = fma(g[k], (double)(cmask[k] ? v1[k] : 0.0f), a1);
                    a2 = fma(g[k], (double)(cmask[k] ? v2[k] : 0.0f), a2);
                }
                hb[0][ph] = a0; hb[1][ph] = a1; hb[2][ph] = a2;
            }
        } else {
            hb[0][ph] = 0.0; hb[1][ph] = 0.0; hb[2][ph] = 0.0;
        }

        // ---- v-blur row rv = r-4 -> vb[c][(ph+2)%3]; tap r-8+k in slot (ph+1+k)%9
        if (doV) {
#pragma unroll
            for (int c = 0; c < 3; ++c) {
                double acc = 0.0;
#pragma unroll
                for (int k = 0; k < 9; ++k)
                    acc = fma(g[k], hb[c][(ph + 1 + k) % 9], acc);
                vb[c][(ph + 2) % 3] = acc;
            }
        }

        // ---- sobel + GM/sector at row ri = r-5
        if (doS) {
            const int ri = r - 5;
            const bool up = RS ? true : (ri >= 1);
            const bool dn = RS ? true : (ri <= HH - 2);
            double mag = 0.0, sgx = 0.0, sgy = 0.0;
#pragma unroll
            for (int c = 0; c < 3; ++c) {
                double top = up ? vb[c][ph % 3]       : 0.0;  // row ri-1
                double mid =      vb[c][(ph + 1) % 3];        // row ri
                double bot = dn ? vb[c][(ph + 2) % 3] : 0.0;  // row ri+1
                double s = top + 2.0 * mid + bot;   // [1,2,1] column sum
                double d = top - bot;               // vertical diff
                double sL = __shfl_up(s, 1), sR = __shfl_down(s, 1);
                double dL = __shfl_up(d, 1), dR = __shfl_down(d, 1);
                if (!CS) {
                    sL = cml ? sL : 0.0;  sR = cmr ? sR : 0.0;
                    dL = cml ? dL : 0.0;  dR = cmr ? dR : 0.0;
                }
                double gx = sL - sR;
                double gy = dL + 2.0 * d + dR;
                mag += sqrt(gx * gx + gy * gy);
                sgx += gx; sgy += gy;
            }
            if (lane_out) {
                size_t o = (size_t)b * HW + (size_t)ri * WW + cl;
                GM[o] = mag;
                double ax = fabs(sgx), ay = fabs(sgy);
                int kp;
                if (ay <= ax * t225)      kp = (sgx >= 0.0) ? 4 : 0;
                else if (ay >= ax * t675) kp = (sgy > 0.0) ? 6 : 2;
                else if (sgx > 0.0)       kp = (sgy > 0.0) ? 5 : 3;
                else                      kp = (sgy > 0.0) ? 7 : 1;
                KP[o] = (unsigned char)kp;
            }
        }
    };

    // chunk 0: rows R0-5 .. R0+3 — H only; V starts at ph 8 (rv = R0-1)
    {
        const int rb = R0 - 5;
#pragma unroll
        for (int ph = 0; ph < 9; ++ph) PHASE(rb + ph, ph, ph == 8, false);
    }
    // chunk 1: rows R0+4 .. R0+12 — H+V; S from ph 1 (ri = R0)
    {
        const int rb = R0 + 4;
#pragma unroll
        for (int ph = 0; ph < 9; ++ph) PHASE(rb + ph, ph, true, ph >= 1);
    }
    // chunk 2: rows R0+13 .. R0+20 (8 phases) — H+V+S
    {
        const int rb = R0 + 13;
#pragma unroll
        for (int ph = 0; ph < 8; ++ph) PHASE(rb + ph, ph, true, true);
    }
}

__global__ __launch_bounds__(256) void canny_gm_kernel(
    const float* __restrict__ img, const float* __restrict__ gwin,
    double* __restrict__ GM, unsigned char* __restrict__ KP)
{
    const int lane = threadIdx.x & 63;
    const int wv   = threadIdx.x >> 6;            // 0..3
    const int cs   = blockIdx.x % NCOLS;
    const int rs   = (blockIdx.x / NCOLS) * 4 + wv;
    const int b    = blockIdx.y;

    const int R0 = rs * RSTRIP;
    const int cl = cs * CSTRIP - 1 + lane;        // this lane's blur column

    double g[9];
#pragma unroll
    for (int k = 0; k < 9; ++k) g[k] = (double)gwin[k];

    const float* ip0 = img + ((size_t)b * NC + 0) * HW;
    const float* ip1 = img + ((size_t)b * NC + 1) * HW;
    const float* ip2 = img + ((size_t)b * NC + 2) * HW;

    const bool csafe = (cs >= 1) && (cs <= NCOLS - 2);
    const bool rsafe = (rs >= 1) && (rs <= NROWS - 2);

    if (csafe) {
        if (rsafe) gm_strip<true, true >(ip0, ip1, ip2, g, lane, R0, cl, b, GM, KP);
        else       gm_strip<true, false>(ip0, ip1, ip2, g, lane, R0, cl, b, GM, KP);
    } else {
        if (rsafe) gm_strip<false, true >(ip0, ip1, ip2, g, lane, R0, cl, b, GM, KP);
        else       gm_strip<false, false>(ip0, ip1, ip2, g, lane, R0, cl, b, GM, KP);
    }
}

// K2: faithful replication of the flat gather (batch<->direction swap):
// pos(b,i,j) = GM[kp,i,j] - GM[kp, i+dr(b), j+dc(b)] (0 if neighbor OOB)
// neg uses kn = (kp+4)&7. thin = min(pos,neg)>0 ? GM[b,i,j] : 0.
// code bit0: thin > 0.3 ; bit1: 0.1 <= thin <= 0.3
__global__ __launch_bounds__(256) void canny_thin_kernel(
    const double* __restrict__ GM, const unsigned char* __restrict__ KP,
    unsigned char* __restrict__ CODE)
{
    int idx = blockIdx.x * blockDim.x + threadIdx.x;
    if (idx >= NB * HW) return;
    int j = idx & (WW - 1);
    int i = (idx >> 9) & (HH - 1);
    int b = idx >> 18;

    // dr+1 per b (digits b7..b0): 0,0,0,1,2,2,2,1 ; dc+1: 2,1,0,0,0,1,2,2
    int dr = (int)((0x00012221u >> (b * 4)) & 15u) - 1;
    int dc = (int)((0x21000122u >> (b * 4)) & 15u) - 1;

    int kp = KP[idx];
    int kn = (kp + 4) & 7;
    int ni = i + dr, nj = j + dc;
    bool nin = ((unsigned)ni < (unsigned)HH) && ((unsigned)nj < (unsigned)WW);
    size_t p0 = (size_t)i * WW + j;
    size_t pn = (size_t)ni * WW + nj;

    double gmp  = GM[(size_t)kp * HW + p0];
    double gmn  = GM[(size_t)kn * HW + p0];
    double gmpn = nin ? GM[(size_t)kp * HW + pn] : 0.0;
    double gmnn = nin ? GM[(size_t)kn * HW + pn] : 0.0;

    double pos = gmp - gmpn;
    double neg = gmn - gmnn;
    double thin = (fmin(pos, neg) > 0.0) ? GM[idx] : 0.0;

    unsigned char code = 0;
    if (thin > 0.3) code |= 1;
    if (thin >= 0.1 && thin <= 0.3) code |= 2;
    CODE[idx] = code;
}

// K3: out = !border && (higher || (middle && any 8-neighbor higher))
__global__ __launch_bounds__(256) void canny_out_kernel(
    const unsigned char* __restrict__ CODE, float* __restrict__ out)
{
    int idx = blockIdx.x * blockDim.x + threadIdx.x;
    if (idx >= NB * HW) return;
    int j = idx & (WW - 1);
    int i = (idx >> 9) & (HH - 1);
    int b = idx >> 18;

    float r = 0.0f;
    if (i > 0 && i < HH - 1 && j > 0 && j < WW - 1) {
        unsigned char c = CODE[idx];
        if (c & 1) {
            r = 1.0f;
        } else if (c & 2) {
            const unsigned char* base = CODE + (size_t)b * HW;
            int any = 0;
            any |= base[(size_t)(i-1)*WW + (j-1)] & 1;
            any |= base[(size_t)(i-1)*WW + (j  )] & 1;
            any |= base[(size_t)(i-1)*WW + (j+1)] & 1;
            any |= base[(size_t)(i  )*WW + (j-1)] & 1;
            any |= base[(size_t)(i  )*WW + (j+1)] & 1;
            any |= base[(size_t)(i+1)*WW + (j-1)] & 1;
            any |= base[(size_t)(i+1)*WW + (j  )] & 1;
            any |= base[(size_t)(i+1)*WW + (j+1)] & 1;
            if (any) r = 1.0f;
        }
    }
    out[idx] = r;
}

extern "C" void kernel_launch(void* const* d_in, const int* in_sizes, int n_in,
                              void* d_out, int out_size, void* d_ws, size_t ws_size,
                              hipStream_t stream) {
    const float* img  = (const float*)d_in[0];
    const float* gwin = (const float*)d_in[1];

    double* GM = (double*)d_ws;
    unsigned char* KP = (unsigned char*)d_ws + (size_t)NB * HW * sizeof(double);
    unsigned char* CODE = KP + (size_t)NB * HW;
    float* out = (float*)d_out;

    dim3 g1(NCOLS * (NROWS / 4), NB);   // (72, 8) blocks x 256 threads
    canny_gm_kernel<<<g1, 256, 0, stream>>>(img, gwin, GM, KP);

    int nblk = (NB * HW) / 256;
    canny_thin_kernel<<<nblk, 256, 0, stream>>>(GM, KP, CODE);
    canny_out_kernel<<<nblk, 256, 0, stream>>>(CODE, out);
}

// Round 6
// 73.255 us; speedup vs baseline: 1.3135x; 1.3135x over previous
//
#include <hip/hip_runtime.h>
#include <math.h>

#define HH 512
#define WW 512
#define NB 8
#define NC 3
#define HW (HH*WW)

#define RSTRIP 8                          // output rows per wave
#define CSTRIP 62                         // output cols per wave
#define NROWS (HH/RSTRIP)                 // 64
#define NCOLS ((WW + CSTRIP - 1)/CSTRIP)  // 9

// K1: register row-streaming separable conv; one 64-lane wave per 62x8 strip.
// Per img row: h-blur (9 masked global f32 loads -> f64 fma) into a 9-deep
// register ring; v-blur (9 f64 fma) into a 3-deep ring; sobel via __shfl on
// s=[1,2,1]col-sum / d=top-bot (r5-proven refactor). f64 end-to-end.
__global__ __launch_bounds__(64) void canny_gm_kernel(
    const float* __restrict__ img, const float* __restrict__ gwin,
    double* __restrict__ GM, unsigned char* __restrict__ KP)
{
    const int lane = threadIdx.x;              // 0..63
    const int cs   = blockIdx.x % NCOLS;
    const int rs   = blockIdx.x / NCOLS;
    const int b    = blockIdx.y;

    const int R0 = rs * RSTRIP;
    const int cl = cs * CSTRIP - 1 + lane;     // this lane's blur column

    double g[9];
#pragma unroll
    for (int k = 0; k < 9; ++k) g[k] = (double)gwin[k];

    // 9-tap column window: clamped indices + masks
    int cidx[9]; bool cmask[9];
#pragma unroll
    for (int k = 0; k < 9; ++k) {
        int cc = cl - 4 + k;
        cmask[k] = ((unsigned)cc < (unsigned)WW);
        int cc2 = cc < 0 ? 0 : cc;
        cidx[k] = cc2 > (WW - 1) ? (WW - 1) : cc2;
    }
    const bool lane_out = (lane >= 1) && (lane <= CSTRIP) && (cl < WW);
    const bool cml = ((unsigned)(cl - 1) < (unsigned)WW);
    const bool cmr = ((unsigned)(cl + 1) < (unsigned)WW);

    const float* ip0 = img + ((size_t)b * NC + 0) * HW;
    const float* ip1 = img + ((size_t)b * NC + 1) * HW;
    const float* ip2 = img + ((size_t)b * NC + 2) * HW;

    double hb[3][9];   // h-blur ring: slot = phase
    double vb[3][3];   // v-blur ring: row rv -> slot (rv - R0 + 2) % 3
#pragma unroll
    for (int c = 0; c < 3; ++c) {
#pragma unroll
        for (int k = 0; k < 9; ++k) hb[c][k] = 0.0;
#pragma unroll
        for (int k = 0; k < 3; ++k) vb[c][k] = 0.0;
    }

    const double t225 = 0.41421356237309503;   // tan(22.5 deg)
    const double t675 = 2.414213562373095;     // tan(67.5 deg)

    auto PHASE = [&](int r, int ph, bool doV, bool doS) {
        // ---- h-blur of img row r -> hb[c][ph] (zero outside image)
        if ((unsigned)r < (unsigned)HH) {
            const size_t ro = (size_t)r * WW;
            float v0[9], v1[9], v2[9];
#pragma unroll
            for (int k = 0; k < 9; ++k) {
                v0[k] = ip0[ro + cidx[k]];
                v1[k] = ip1[ro + cidx[k]];
                v2[k] = ip2[ro + cidx[k]];
            }
            double a0 = 0.0, a1 = 0.0, a2 = 0.0;
#pragma unroll
            for (int k = 0; k < 9; ++k) {
                a0 = fma(g[k], (double)(cmask[k] ? v0[k] : 0.0f), a0);
                a1 = fma(g[k], (double)(cmask[k] ? v1[k] : 0.0f), a1);
                a2 = fma(g[k], (double)(cmask[k] ? v2[k] : 0.0f), a2);
            }
            hb[0][ph] = a0; hb[1][ph] = a1; hb[2][ph] = a2;
        } else {
            hb[0][ph] = 0.0; hb[1][ph] = 0.0; hb[2][ph] = 0.0;
        }

        // ---- v-blur row rv = r-4 -> vb[c][(ph+2)%3]; tap r-8+k in slot (ph+1+k)%9
        if (doV) {
#pragma unroll
            for (int c = 0; c < 3; ++c) {
                double acc = 0.0;
#pragma unroll
                for (int k = 0; k < 9; ++k)
                    acc = fma(g[k], hb[c][(ph + 1 + k) % 9], acc);
                vb[c][(ph + 2) % 3] = acc;
            }
        }

        // ---- sobel + GM/sector at row ri = r-5
        if (doS) {
            const int ri = r - 5;
            const bool up = (ri >= 1), dn = (ri <= HH - 2);
            double mag = 0.0, sgx = 0.0, sgy = 0.0;
#pragma unroll
            for (int c = 0; c < 3; ++c) {
                double top = up ? vb[c][ph % 3]       : 0.0;  // row ri-1
                double mid =      vb[c][(ph + 1) % 3];        // row ri
                double bot = dn ? vb[c][(ph + 2) % 3] : 0.0;  // row ri+1
                double s = top + 2.0 * mid + bot;   // [1,2,1] column sum
                double d = top - bot;               // vertical diff
                double sL = __shfl_up(s, 1), sR = __shfl_down(s, 1);
                double dL = __shfl_up(d, 1), dR = __shfl_down(d, 1);
                sL = cml ? sL : 0.0;  sR = cmr ? sR : 0.0;
                dL = cml ? dL : 0.0;  dR = cmr ? dR : 0.0;
                double gx = sL - sR;
                double gy = dL + 2.0 * d + dR;
                mag += sqrt(gx * gx + gy * gy);
                sgx += gx; sgy += gy;
            }
            if (lane_out) {
                size_t o = (size_t)b * HW + (size_t)ri * WW + cl;
                GM[o] = mag;
                double ax = fabs(sgx), ay = fabs(sgy);
                int kp;
                if (ay <= ax * t225)      kp = (sgx >= 0.0) ? 4 : 0;
                else if (ay >= ax * t675) kp = (sgy > 0.0) ? 6 : 2;
                else if (sgx > 0.0)       kp = (sgy > 0.0) ? 5 : 3;
                else                      kp = (sgy > 0.0) ? 7 : 1;
                KP[o] = (unsigned char)kp;
            }
        }
    };

    // chunk 0: rows R0-5 .. R0+3 — H; V starts at ph 8 (rv = R0-1)
    {
        const int rb = R0 - 5;
#pragma unroll
        for (int ph = 0; ph < 9; ++ph) PHASE(rb + ph, ph, ph == 8, false);
    }
    // chunk 1: rows R0+4 .. R0+12 — H+V; S from ph 1 (ri = R0 .. R0+7)
    {
        const int rb = R0 + 4;
#pragma unroll
        for (int ph = 0; ph < 9; ++ph) PHASE(rb + ph, ph, true, ph >= 1);
    }
}

// K23 fused: per 32x32 tile, compute the 34x34 halo of CODE bytes into LDS
// (thin/threshold decisions, identical to proven K2), then hysteresis (K3).
// code bit0: thin > 0.3 ; bit1: 0.1 <= thin <= 0.3
__global__ __launch_bounds__(256) void canny_thin_out_kernel(
    const double* __restrict__ GM, const unsigned char* __restrict__ KP,
    float* __restrict__ out)
{
    __shared__ unsigned char scode[34 * 35];

    const int tilesX = WW / 32;                 // 16
    const int tx0 = (blockIdx.x % tilesX) * 32;
    const int ty0 = (blockIdx.x / tilesX) * 32;
    const int b = blockIdx.y;
    const int t = threadIdx.x;

    // dr+1 per b (digits b7..b0): 0,0,0,1,2,2,2,1 ; dc+1: 2,1,0,0,0,1,2,2
    const int dr = (int)((0x00012221u >> (b * 4)) & 15u) - 1;
    const int dc = (int)((0x21000122u >> (b * 4)) & 15u) - 1;

    // ---- phase 1: codes for tile+halo (34x34 items, width-34 walk)
    {
        int r = t / 34, cc = t % 34, idx = t;
#pragma unroll
        for (int it = 0; it < 5; ++it) {
            if (idx < 34 * 34) {
                int gi = ty0 - 1 + r, gj = tx0 - 1 + cc;
                unsigned char code = 0;
                if ((unsigned)gi < (unsigned)HH && (unsigned)gj < (unsigned)WW) {
                    size_t p0 = (size_t)gi * WW + gj;
                    int kp = KP[(size_t)b * HW + p0];
                    int kn = (kp + 4) & 7;
                    int ni = gi + dr, nj = gj + dc;
                    bool nin = ((unsigned)ni < (unsigned)HH) && ((unsigned)nj < (unsigned)WW);
                    size_t pn = (size_t)ni * WW + nj;
                    double gmp  = GM[(size_t)kp * HW + p0];
                    double gmn  = GM[(size_t)kn * HW + p0];
                    double gmpn = nin ? GM[(size_t)kp * HW + pn] : 0.0;
                    double gmnn = nin ? GM[(size_t)kn * HW + pn] : 0.0;
                    double pos = gmp - gmpn;
                    double neg = gmn - gmnn;
                    double thin = (fmin(pos, neg) > 0.0) ? GM[(size_t)b * HW + p0] : 0.0;
                    if (thin > 0.3) code |= 1;
                    if (thin >= 0.1 && thin <= 0.3) code |= 2;
                }
                scode[r * 35 + cc] = code;
            }
            idx += 256; r += 7; cc += 18;        // 256 = 7*34 + 18
            if (cc >= 34) { cc -= 34; ++r; }
        }
    }
    __syncthreads();

    // ---- phase 2: hysteresis + border zero, 4 px/thread
#pragma unroll
    for (int p = 0; p < 4; ++p) {
        int pix = t + p * 256;
        int i = pix >> 5, j = pix & 31;
        int gi = ty0 + i, gj = tx0 + j;
        float res = 0.0f;
        if (gi > 0 && gi < HH - 1 && gj > 0 && gj < WW - 1) {
            const unsigned char* sc = scode + (i + 1) * 35 + (j + 1);
            unsigned char c = *sc;
            if (c & 1) {
                res = 1.0f;
            } else if (c & 2) {
                int any = 0;
                any |= sc[-36] & 1; any |= sc[-35] & 1; any |= sc[-34] & 1;
                any |= sc[-1]  & 1; any |= sc[ 1]  & 1;
                any |= sc[ 34] & 1; any |= sc[ 35] & 1; any |= sc[ 36] & 1;
                if (any) res = 1.0f;
            }
        }
        out[(size_t)b * HW + (size_t)gi * WW + gj] = res;
    }
}

extern "C" void kernel_launch(void* const* d_in, const int* in_sizes, int n_in,
                              void* d_out, int out_size, void* d_ws, size_t ws_size,
                              hipStream_t stream) {
    const float* img  = (const float*)d_in[0];
    const float* gwin = (const float*)d_in[1];

    double* GM = (double*)d_ws;
    unsigned char* KP = (unsigned char*)d_ws + (size_t)NB * HW * sizeof(double);
    float* out = (float*)d_out;

    dim3 g1(NCOLS * NROWS, NB);   // (576, 8) = 4608 one-wave blocks
    canny_gm_kernel<<<g1, 64, 0, stream>>>(img, gwin, GM, KP);

    dim3 g2((WW / 32) * (HH / 32), NB);   // (256, 8) blocks x 256
    canny_thin_out_kernel<<<g2, 256, 0, stream>>>(GM, KP, out);
}

// Round 7
// 66.806 us; speedup vs baseline: 1.4403x; 1.0965x over previous
//
#include <hip/hip_runtime.h>
#include <math.h>

#define HH 512
#define WW 512
#define NB 8
#define NC 3
#define HW (HH*WW)

#define RSTRIP 8                          // output rows per wave
#define CSTRIP 62                         // output cols per wave
#define NROWS (HH/RSTRIP)                 // 64
#define NCOLS ((WW + CSTRIP - 1)/CSTRIP)  // 9
#define WPB 4                             // row-strips (waves) per block

// K1: register row-streaming separable conv; one 64-lane wave per 62x8 strip,
// 4 independent waves per block (no LDS, no barriers -> block-slot cap lifted).
// Per img row: h-blur (9 clamped global f32 loads, column mask folded into
// coefficients) into a 9-deep f64 ring; v-blur (9 f64 fma) into a 3-deep ring;
// sobel via __shfl on s=[1,2,1]col-sum / d=top-bot. f64 end-to-end.
__global__ __launch_bounds__(256) void canny_gm_kernel(
    const float* __restrict__ img, const float* __restrict__ gwin,
    double* __restrict__ GM, unsigned char* __restrict__ KP)
{
    const int lane = threadIdx.x & 63;
    const int wv   = threadIdx.x >> 6;         // 0..3
    const int cs   = blockIdx.x % NCOLS;
    const int rs   = (blockIdx.x / NCOLS) * WPB + wv;
    const int b    = blockIdx.y;

    const int R0 = rs * RSTRIP;
    const int cl = cs * CSTRIP - 1 + lane;     // this lane's blur column

    double g[9];
#pragma unroll
    for (int k = 0; k < 9; ++k) g[k] = (double)gwin[k];

    // 9-tap column window: clamped indices; mask folded into per-lane coeffs
    int cidx[9]; double gk[9];
#pragma unroll
    for (int k = 0; k < 9; ++k) {
        int cc = cl - 4 + k;
        bool m = ((unsigned)cc < (unsigned)WW);
        gk[k] = m ? g[k] : 0.0;                // 0*finite = +/-0 -> acc unchanged
        int cc2 = cc < 0 ? 0 : cc;
        cidx[k] = cc2 > (WW - 1) ? (WW - 1) : cc2;
    }
    const bool lane_out = (lane >= 1) && (lane <= CSTRIP) && (cl < WW);
    const bool cml = ((unsigned)(cl - 1) < (unsigned)WW);
    const bool cmr = ((unsigned)(cl + 1) < (unsigned)WW);

    const float* ip0 = img + ((size_t)b * NC + 0) * HW;
    const float* ip1 = img + ((size_t)b * NC + 1) * HW;
    const float* ip2 = img + ((size_t)b * NC + 2) * HW;

    double hb[3][9];   // h-blur ring: slot = phase
    double vb[3][3];   // v-blur ring
#pragma unroll
    for (int c = 0; c < 3; ++c) {
#pragma unroll
        for (int k = 0; k < 9; ++k) hb[c][k] = 0.0;
#pragma unroll
        for (int k = 0; k < 3; ++k) vb[c][k] = 0.0;
    }

    const double t225 = 0.41421356237309503;   // tan(22.5 deg)
    const double t675 = 2.414213562373095;     // tan(67.5 deg)

    auto PHASE = [&](int r, int ph, bool doV, bool doS) {
        // ---- h-blur of img row r -> hb[c][ph] (zero outside image)
        if ((unsigned)r < (unsigned)HH) {
            const size_t ro = (size_t)r * WW;
            float v0[9], v1[9], v2[9];
#pragma unroll
            for (int k = 0; k < 9; ++k) {
                v0[k] = ip0[ro + cidx[k]];
                v1[k] = ip1[ro + cidx[k]];
                v2[k] = ip2[ro + cidx[k]];
            }
            double a0 = 0.0, a1 = 0.0, a2 = 0.0;
#pragma unroll
            for (int k = 0; k < 9; ++k) {
                a0 = fma(gk[k], (double)v0[k], a0);
                a1 = fma(gk[k], (double)v1[k], a1);
                a2 = fma(gk[k], (double)v2[k], a2);
            }
            hb[0][ph] = a0; hb[1][ph] = a1; hb[2][ph] = a2;
        } else {
            hb[0][ph] = 0.0; hb[1][ph] = 0.0; hb[2][ph] = 0.0;
        }

        // ---- v-blur row rv = r-4 -> vb[c][(ph+2)%3]; tap r-8+k in slot (ph+1+k)%9
        if (doV) {
#pragma unroll
            for (int c = 0; c < 3; ++c) {
                double acc = 0.0;
#pragma unroll
                for (int k = 0; k < 9; ++k)
                    acc = fma(g[k], hb[c][(ph + 1 + k) % 9], acc);
                vb[c][(ph + 2) % 3] = acc;
            }
        }

        // ---- sobel + GM/sector at row ri = r-5
        if (doS) {
            const int ri = r - 5;
            const bool up = (ri >= 1), dn = (ri <= HH - 2);
            double mag = 0.0, sgx = 0.0, sgy = 0.0;
#pragma unroll
            for (int c = 0; c < 3; ++c) {
                double top = up ? vb[c][ph % 3]       : 0.0;  // row ri-1
                double mid =      vb[c][(ph + 1) % 3];        // row ri
                double bot = dn ? vb[c][(ph + 2) % 3] : 0.0;  // row ri+1
                double s = top + 2.0 * mid + bot;   // [1,2,1] column sum
                double d = top - bot;               // vertical diff
                double sL = __shfl_up(s, 1), sR = __shfl_down(s, 1);
                double dL = __shfl_up(d, 1), dR = __shfl_down(d, 1);
                sL = cml ? sL : 0.0;  sR = cmr ? sR : 0.0;
                dL = cml ? dL : 0.0;  dR = cmr ? dR : 0.0;
                double gx = sL - sR;
                double gy = dL + 2.0 * d + dR;
                mag += sqrt(gx * gx + gy * gy);
                sgx += gx; sgy += gy;
            }
            if (lane_out) {
                size_t o = (size_t)b * HW + (size_t)ri * WW + cl;
                GM[o] = mag;
                double ax = fabs(sgx), ay = fabs(sgy);
                int kp;
                if (ay <= ax * t225)      kp = (sgx >= 0.0) ? 4 : 0;
                else if (ay >= ax * t675) kp = (sgy > 0.0) ? 6 : 2;
                else if (sgx > 0.0)       kp = (sgy > 0.0) ? 5 : 3;
                else                      kp = (sgy > 0.0) ? 7 : 1;
                KP[o] = (unsigned char)kp;
            }
        }
    };

    // chunk 0: rows R0-5 .. R0+3 — H; V starts at ph 8 (rv = R0-1)
    {
        const int rb = R0 - 5;
#pragma unroll
        for (int ph = 0; ph < 9; ++ph) PHASE(rb + ph, ph, ph == 8, false);
    }
    // chunk 1: rows R0+4 .. R0+12 — H+V; S from ph 1 (ri = R0 .. R0+7)
    {
        const int rb = R0 + 4;
#pragma unroll
        for (int ph = 0; ph < 9; ++ph) PHASE(rb + ph, ph, true, ph >= 1);
    }
}

// K23 fused: per 32x32 tile, compute the 34x34 halo of CODE bytes into LDS
// (thin/threshold decisions, identical to proven K2), then hysteresis (K3).
// code bit0: thin > 0.3 ; bit1: 0.1 <= thin <= 0.3
__global__ __launch_bounds__(256) void canny_thin_out_kernel(
    const double* __restrict__ GM, const unsigned char* __restrict__ KP,
    float* __restrict__ out)
{
    __shared__ unsigned char scode[34 * 35];

    const int tilesX = WW / 32;                 // 16
    const int tx0 = (blockIdx.x % tilesX) * 32;
    const int ty0 = (blockIdx.x / tilesX) * 32;
    const int b = blockIdx.y;
    const int t = threadIdx.x;

    // dr+1 per b (digits b7..b0): 0,0,0,1,2,2,2,1 ; dc+1: 2,1,0,0,0,1,2,2
    const int dr = (int)((0x00012221u >> (b * 4)) & 15u) - 1;
    const int dc = (int)((0x21000122u >> (b * 4)) & 15u) - 1;

    // ---- phase 1: codes for tile+halo (34x34 items, width-34 walk)
    {
        int r = t / 34, cc = t % 34, idx = t;
#pragma unroll
        for (int it = 0; it < 5; ++it) {
            if (idx < 34 * 34) {
                int gi = ty0 - 1 + r, gj = tx0 - 1 + cc;
                unsigned char code = 0;
                if ((unsigned)gi < (unsigned)HH && (unsigned)gj < (unsigned)WW) {
                    size_t p0 = (size_t)gi * WW + gj;
                    int kp = KP[(size_t)b * HW + p0];
                    int kn = (kp + 4) & 7;
                    int ni = gi + dr, nj = gj + dc;
                    bool nin = ((unsigned)ni < (unsigned)HH) && ((unsigned)nj < (unsigned)WW);
                    size_t pn = (size_t)ni * WW + nj;
                    double gmp  = GM[(size_t)kp * HW + p0];
                    double gmn  = GM[(size_t)kn * HW + p0];
                    double gmpn = nin ? GM[(size_t)kp * HW + pn] : 0.0;
                    double gmnn = nin ? GM[(size_t)kn * HW + pn] : 0.0;
                    double pos = gmp - gmpn;
                    double neg = gmn - gmnn;
                    double thin = (fmin(pos, neg) > 0.0) ? GM[(size_t)b * HW + p0] : 0.0;
                    if (thin > 0.3) code |= 1;
                    if (thin >= 0.1 && thin <= 0.3) code |= 2;
                }
                scode[r * 35 + cc] = code;
            }
            idx += 256; r += 7; cc += 18;        // 256 = 7*34 + 18
            if (cc >= 34) { cc -= 34; ++r; }
        }
    }
    __syncthreads();

    // ---- phase 2: hysteresis + border zero, 4 px/thread
#pragma unroll
    for (int p = 0; p < 4; ++p) {
        int pix = t + p * 256;
        int i = pix >> 5, j = pix & 31;
        int gi = ty0 + i, gj = tx0 + j;
        float res = 0.0f;
        if (gi > 0 && gi < HH - 1 && gj > 0 && gj < WW - 1) {
            const unsigned char* sc = scode + (i + 1) * 35 + (j + 1);
            unsigned char c = *sc;
            if (c & 1) {
                res = 1.0f;
            } else if (c & 2) {
                int any = 0;
                any |= sc[-36] & 1; any |= sc[-35] & 1; any |= sc[-34] & 1;
                any |= sc[-1]  & 1; any |= sc[ 1]  & 1;
                any |= sc[ 34] & 1; any |= sc[ 35] & 1; any |= sc[ 36] & 1;
                if (any) res = 1.0f;
            }
        }
        out[(size_t)b * HW + (size_t)gi * WW + gj] = res;
    }
}

extern "C" void kernel_launch(void* const* d_in, const int* in_sizes, int n_in,
                              void* d_out, int out_size, void* d_ws, size_t ws_size,
                              hipStream_t stream) {
    const float* img  = (const float*)d_in[0];
    const float* gwin = (const float*)d_in[1];

    double* GM = (double*)d_ws;
    unsigned char* KP = (unsigned char*)d_ws + (size_t)NB * HW * sizeof(double);
    float* out = (float*)d_out;

    dim3 g1(NCOLS * (NROWS / WPB), NB);   // (144, 8) = 1152 blocks x 256 thr
    canny_gm_kernel<<<g1, 256, 0, stream>>>(img, gwin, GM, KP);

    dim3 g2((WW / 32) * (HH / 32), NB);   // (256, 8) blocks x 256
    canny_thin_out_kernel<<<g2, 256, 0, stream>>>(GM, KP, out);
}